// Round 5
// baseline (143.272 us; speedup 1.0000x reference)
//
#include <hip/hip_runtime.h>

// Shapes from reference: n=32, p2=49, topk=4, w2=64, c_kv=256
// out[b,p,t,w,c] = r_weight[b,p,t] * kv[b, r_idx[b,p,t], w, c]
constexpr int N    = 32;
constexpr int P2   = 49;
constexpr int TOPK = 4;
constexpr int W2   = 64;
constexpr int CKV  = 256;
constexpr int ROW  = W2 * CKV;      // 16384 floats per gathered slab (64 KB)
constexpr int ROW4 = ROW / 4;       // 4096 float4 per slab
constexpr int G    = N * P2 * TOPK; // 6272 (b,p,t) tuples
constexpr int SPB  = 4;             // slabs per block; 4 | P2*TOPK so one b/block
constexpr int NBLK = G / SPB;       // 1568 blocks

typedef float floatx4 __attribute__((ext_vector_type(4)));

__global__ __launch_bounds__(256)
void kv_gather_scale(const int* __restrict__ r_idx,
                     const float* __restrict__ r_weight,
                     const float* __restrict__ kv,
                     float* __restrict__ out) {
    const int base = blockIdx.x * SPB;        // first flat (b,p,t) of this block
    const int b    = base / (P2 * TOPK);      // shared by all 4 slabs (4 | 196)

    // Batch the index/weight loads up front — one serial-latency exposure
    // per block instead of four.
    int   src[SPB];
    float w[SPB];
    #pragma unroll
    for (int k = 0; k < SPB; ++k) {
        src[k] = r_idx[base + k];
        w[k]   = r_weight[base + k];
    }

    const floatx4* __restrict__ kv4  = (const floatx4*)kv;
    floatx4* __restrict__       out4 = (floatx4*)out;

    // Outer loop rolled (caps VGPR at ~16 float4 in flight); inner fully
    // unrolled: 16 coalesced dwordx4 loads issue back-to-back, then stores.
    // Slab k+1's loads issue right after slab k's stores (stores don't stall).
    #pragma unroll 1
    for (int k = 0; k < SPB; ++k) {
        const floatx4* __restrict__ s = kv4 + (size_t)(b * P2 + src[k]) * ROW4;
        floatx4* __restrict__       d = out4 + (size_t)(base + k) * ROW4;
        #pragma unroll
        for (int i = threadIdx.x; i < ROW4; i += 256) {
            d[i] = s[i] * w[k];
        }
    }
}

extern "C" void kernel_launch(void* const* d_in, const int* in_sizes, int n_in,
                              void* d_out, int out_size, void* d_ws, size_t ws_size,
                              hipStream_t stream) {
    const int*   r_idx    = (const int*)d_in[0];
    const float* r_weight = (const float*)d_in[1];
    const float* kv       = (const float*)d_in[2];
    float*       out      = (float*)d_out;

    kv_gather_scale<<<NBLK, 256, 0, stream>>>(r_idx, r_weight, kv, out);
}

// Round 6
// 112.576 us; speedup vs baseline: 1.2727x; 1.2727x over previous
//
#include <hip/hip_runtime.h>

// Shapes from reference: n=32, p2=49, topk=4, w2=64, c_kv=256
// out[b,p,t,w,c] = r_weight[b,p,t] * kv[b, r_idx[b,p,t], w, c]
constexpr int N    = 32;
constexpr int P2   = 49;
constexpr int TOPK = 4;
constexpr int W2   = 64;
constexpr int CKV  = 256;
constexpr int ROW  = W2 * CKV;      // 16384 floats per gathered slab (64 KB)
constexpr int ROW4 = ROW / 4;       // 4096 float4 per slab
constexpr int G    = N * P2 * TOPK; // 6272 (b,p,t) tuples
constexpr int HALF4 = ROW4 / 2;     // 2048 float4 per half-slab (32 KB)
constexpr int NBLK = G * 2;         // 12544 blocks, one half-slab each

typedef float floatx4 __attribute__((ext_vector_type(4)));

__global__ __launch_bounds__(256)
void kv_gather_scale(const int* __restrict__ r_idx,
                     const float* __restrict__ r_weight,
                     const float* __restrict__ kv,
                     float* __restrict__ out) {
    const int bid  = blockIdx.x;
    const int g    = bid >> 1;                // flat (b, p, t)
    const int half = bid & 1;                 // which 32 KB half of the slab
    const int b    = g / (P2 * TOPK);

    const int   src = r_idx[g];               // source p-row in [0, P2)
    const float w   = r_weight[g];

    const int off = half * HALF4;
    const floatx4* __restrict__ s =
        (const floatx4*)(kv + (size_t)(b * P2 + src) * ROW) + off;
    floatx4* __restrict__ d = (floatx4*)(out + (size_t)g * ROW) + off;

    // 8 float4 per thread; identical coalescing to R1, half the per-block
    // serial chain and twice the dispatch grain.
    #pragma unroll
    for (int i = threadIdx.x; i < HALF4; i += 256) {
        d[i] = s[i] * w;
    }
}

extern "C" void kernel_launch(void* const* d_in, const int* in_sizes, int n_in,
                              void* d_out, int out_size, void* d_ws, size_t ws_size,
                              hipStream_t stream) {
    const int*   r_idx    = (const int*)d_in[0];
    const float* r_weight = (const float*)d_in[1];
    const float* kv       = (const float*)d_in[2];
    float*       out      = (float*)d_out;

    kv_gather_scale<<<NBLK, 256, 0, stream>>>(r_idx, r_weight, kv, out);
}